// Round 1
// baseline (3557.250 us; speedup 1.0000x reference)
//
#include <hip/hip_runtime.h>

static constexpr int DIN = 64;
static constexpr int H1  = 256;
static constexpr int H2  = 128;

// ---------------- degree + dinv ----------------
__global__ void k_deg(const int* __restrict__ dst, float* __restrict__ deg, int E) {
  int e = blockIdx.x * blockDim.x + threadIdx.x;
  if (e < E) atomicAdd(&deg[dst[e]], 1.0f);
}

__global__ void k_dinv(float* __restrict__ deg, int N) {
  int i = blockIdx.x * blockDim.x + threadIdx.x;
  if (i < N) deg[i] = rsqrtf(deg[i] + 1.0f);   // deg includes self-loop
}

// ---------------- simple LDS-tiled GEMM: C[M,NOUT] = A[M,K] @ W[K,NOUT] ----------------
// blockDim.x == NOUT, each block does ROWS rows.
template<int K, int NOUT, int ROWS>
__global__ void k_gemm(const float* __restrict__ A, const float* __restrict__ W,
                       float* __restrict__ C, int M) {
  __shared__ float As[ROWS * K];
  const int row0 = blockIdx.x * ROWS;
  const int tid  = threadIdx.x;
  for (int idx = tid; idx < ROWS * K; idx += NOUT) {
    int r = idx / K;
    As[idx] = (row0 + r < M) ? A[(size_t)row0 * K + idx] : 0.0f;
  }
  __syncthreads();
  float acc[ROWS];
#pragma unroll
  for (int r = 0; r < ROWS; ++r) acc[r] = 0.0f;
  for (int k = 0; k < K; ++k) {
    float w = W[k * NOUT + tid];           // coalesced, L2-resident
#pragma unroll
    for (int r = 0; r < ROWS; ++r) acc[r] = fmaf(As[r * K + k], w, acc[r]); // LDS broadcast
  }
#pragma unroll
  for (int r = 0; r < ROWS; ++r) {
    int m = row0 + r;
    if (m < M) C[(size_t)m * NOUT + tid] = acc[r];
  }
}

// ---------------- self-loop term: agg[i,c] = xw[i,c] * dinv[i]^2 ----------------
template<int C>
__global__ void k_self(const float* __restrict__ xw, const float* __restrict__ dinv,
                       float* __restrict__ agg, int N) {
  size_t i = (size_t)blockIdx.x * blockDim.x + threadIdx.x;
  size_t total = (size_t)N * C;
  if (i < total) {
    int row = (int)(i / C);
    float dv = dinv[row];
    agg[i] = xw[i] * dv * dv;
  }
}

// ---------------- edge scatter: agg[dst] += xw[src] * dinv[src]*dinv[dst] ----------------
// one wave (64 lanes) per edge; each lane handles C/64 contiguous channels.
template<int C>
__global__ void k_scatter(const int* __restrict__ src, const int* __restrict__ dst,
                          const float* __restrict__ dinv,
                          const float* __restrict__ xw, float* __restrict__ agg, int E) {
  constexpr int VPL = C / 64;
  int wave = (int)((blockIdx.x * (size_t)blockDim.x + threadIdx.x) >> 6);
  int lane = threadIdx.x & 63;
  if (wave >= E) return;
  int s = src[wave], d = dst[wave];
  float coef = dinv[s] * dinv[d];
  const float* xs = xw + (size_t)s * C + lane * VPL;
  float* ad = agg + (size_t)d * C + lane * VPL;
  if constexpr (VPL == 4) {
    float4 v = *reinterpret_cast<const float4*>(xs);
    atomicAdd(ad + 0, v.x * coef);
    atomicAdd(ad + 1, v.y * coef);
    atomicAdd(ad + 2, v.z * coef);
    atomicAdd(ad + 3, v.w * coef);
  } else {
    float2 v = *reinterpret_cast<const float2*>(xs);
    atomicAdd(ad + 0, v.x * coef);
    atomicAdd(ad + 1, v.y * coef);
  }
}

// ---------------- bias + relu, in place ----------------
template<int C, bool RELU>
__global__ void k_bias_act(float* __restrict__ h, const float* __restrict__ b, int N) {
  size_t i = (size_t)blockIdx.x * blockDim.x + threadIdx.x;
  size_t total = (size_t)N * C;
  if (i < total) {
    float v = h[i] + b[i & (C - 1)];
    h[i] = RELU ? fmaxf(v, 0.0f) : v;
  }
}

// ---------------- heads: node_x (direct), p = emb@eW_top, q = emb@eW_bot ----------------
// one wave per node; emb read as agg2 + b2 (bias fused here).
__global__ void k_heads(const float* __restrict__ agg2, const float* __restrict__ b2,
                        const float* __restrict__ nW, const float* __restrict__ nb,
                        const float* __restrict__ eW,
                        float* __restrict__ node_out,
                        float* __restrict__ p, float* __restrict__ q, int N) {
  int wave = (int)((blockIdx.x * (size_t)blockDim.x + threadIdx.x) >> 6);
  int lane = threadIdx.x & 63;
  if (wave >= N) return;
  int c0 = lane, c1 = lane + 64;
  float e0 = agg2[(size_t)wave * H2 + c0] + b2[c0];
  float e1 = agg2[(size_t)wave * H2 + c1] + b2[c1];
  float n0 = e0 * nW[c0 * 2 + 0] + e1 * nW[c1 * 2 + 0];
  float n1 = e0 * nW[c0 * 2 + 1] + e1 * nW[c1 * 2 + 1];
  float p0 = e0 * eW[c0 * 2 + 0] + e1 * eW[c1 * 2 + 0];
  float p1 = e0 * eW[c0 * 2 + 1] + e1 * eW[c1 * 2 + 1];
  float q0 = e0 * eW[(128 + c0) * 2 + 0] + e1 * eW[(128 + c1) * 2 + 0];
  float q1 = e0 * eW[(128 + c0) * 2 + 1] + e1 * eW[(128 + c1) * 2 + 1];
#pragma unroll
  for (int off = 32; off >= 1; off >>= 1) {
    n0 += __shfl_xor(n0, off);
    n1 += __shfl_xor(n1, off);
    p0 += __shfl_xor(p0, off);
    p1 += __shfl_xor(p1, off);
    q0 += __shfl_xor(q0, off);
    q1 += __shfl_xor(q1, off);
  }
  if (lane == 0) {
    node_out[(size_t)wave * 2 + 0] = n0 + nb[0];
    node_out[(size_t)wave * 2 + 1] = n1 + nb[1];
    p[(size_t)wave * 2 + 0] = p0;
    p[(size_t)wave * 2 + 1] = p1;
    q[(size_t)wave * 2 + 0] = q0;
    q[(size_t)wave * 2 + 1] = q1;
  }
}

// ---------------- edge output: out[e] = p[src] + q[dst] + eb ----------------
__global__ void k_edge(const int* __restrict__ src, const int* __restrict__ dst,
                       const float* __restrict__ p, const float* __restrict__ q,
                       const float* __restrict__ eb, float* __restrict__ eout, int E) {
  int e = blockIdx.x * blockDim.x + threadIdx.x;
  if (e < E) {
    int s = src[e], d = dst[e];
    float2 P = *reinterpret_cast<const float2*>(p + (size_t)s * 2);
    float2 Q = *reinterpret_cast<const float2*>(q + (size_t)d * 2);
    float2 o;
    o.x = P.x + Q.x + eb[0];
    o.y = P.y + Q.y + eb[1];
    *reinterpret_cast<float2*>(eout + (size_t)e * 2) = o;
  }
}

extern "C" void kernel_launch(void* const* d_in, const int* in_sizes, int n_in,
                              void* d_out, int out_size, void* d_ws, size_t ws_size,
                              hipStream_t stream) {
  const float* x   = (const float*)d_in[0];
  const int*   ei  = (const int*)d_in[1];
  const float* W1  = (const float*)d_in[2];
  const float* b1  = (const float*)d_in[3];
  const float* W2  = (const float*)d_in[4];
  const float* b2  = (const float*)d_in[5];
  const float* nW  = (const float*)d_in[6];
  const float* nb  = (const float*)d_in[7];
  const float* eW  = (const float*)d_in[8];
  const float* eb  = (const float*)d_in[9];

  const int N = in_sizes[0] / DIN;   // 50000
  const int E = in_sizes[1] / 2;     // 800000
  const int* src = ei;
  const int* dst = ei + E;

  float* ws   = (float*)d_ws;
  float* dinv = ws;                        // N
  float* p    = dinv + N;                  // 2N
  float* q    = p + 2 * (size_t)N;         // 2N
  float* xw1  = q + 2 * (size_t)N;         // 256N (reused: xw2 | agg2)
  float* agg1 = xw1 + (size_t)H1 * N;      // 256N (h after bias+relu)
  float* xw2  = xw1;                       // 128N
  float* agg2 = xw1 + (size_t)H2 * N;      // 128N

  float* node_out = (float*)d_out;             // 2N
  float* edge_out = (float*)d_out + 2 * (size_t)N;  // 2E

  // deg -> dinv
  hipMemsetAsync(dinv, 0, (size_t)N * sizeof(float), stream);
  k_deg<<<(E + 255) / 256, 256, 0, stream>>>(dst, dinv, E);
  k_dinv<<<(N + 255) / 256, 256, 0, stream>>>(dinv, N);

  // layer 1
  k_gemm<DIN, H1, 8><<<(N + 7) / 8, H1, 0, stream>>>(x, W1, xw1, N);
  k_self<H1><<<(int)(((size_t)N * H1 + 255) / 256), 256, 0, stream>>>(xw1, dinv, agg1, N);
  k_scatter<H1><<<(E + 3) / 4, 256, 0, stream>>>(src, dst, dinv, xw1, agg1, E);
  k_bias_act<H1, true><<<(int)(((size_t)N * H1 + 255) / 256), 256, 0, stream>>>(agg1, b1, N);

  // layer 2 (xw2 overwrites xw1 region; agg2 in its second half)
  k_gemm<H1, H2, 8><<<(N + 7) / 8, H2, 0, stream>>>(agg1, W2, xw2, N);
  k_self<H2><<<(int)(((size_t)N * H2 + 255) / 256), 256, 0, stream>>>(xw2, dinv, agg2, N);
  k_scatter<H2><<<(E + 3) / 4, 256, 0, stream>>>(src, dst, dinv, xw2, agg2, E);

  // heads (b2 fused), then edge output
  k_heads<<<(N + 3) / 4, 256, 0, stream>>>(agg2, b2, nW, nb, eW, node_out, p, q, N);
  k_edge<<<(E + 255) / 256, 256, 0, stream>>>(src, dst, p, q, eb, edge_out, E);
}

// Round 2
// 524.440 us; speedup vs baseline: 6.7830x; 6.7830x over previous
//
#include <hip/hip_runtime.h>

static constexpr int DIN = 64;
static constexpr int H1  = 256;
static constexpr int H2  = 128;

// ---------------- degree histogram (int) ----------------
__global__ void k_hist(const int* __restrict__ dst, int* __restrict__ hist, int E) {
  int e = blockIdx.x * blockDim.x + threadIdx.x;
  if (e < E) atomicAdd(&hist[dst[e]], 1);
}

__global__ void k_dinv(const int* __restrict__ hist, float* __restrict__ dinv, int N) {
  int i = blockIdx.x * blockDim.x + threadIdx.x;
  if (i < N) dinv[i] = rsqrtf((float)hist[i] + 1.0f);   // +1 self-loop
}

// ---------------- exclusive scan of hist -> offs[0..N], single block 1024 thr ----------------
__global__ void k_scan(const int* __restrict__ hist, int* __restrict__ offs, int N) {
  __shared__ int wsum[16];
  const int t = threadIdx.x;
  const int EPT = (N + 1023) >> 10;
  const int base = t * EPT;
  int sum = 0;
  for (int k = 0; k < EPT; ++k) {
    int i = base + k;
    if (i < N) sum += hist[i];
  }
  int lane = t & 63, wid = t >> 6;
  int v = sum;
#pragma unroll
  for (int off = 1; off < 64; off <<= 1) {
    int u = __shfl_up(v, off);
    if (lane >= off) v += u;
  }
  if (lane == 63) wsum[wid] = v;
  __syncthreads();
  if (t < 16) {
    int w = wsum[t];
#pragma unroll
    for (int off = 1; off < 16; off <<= 1) {
      int u = __shfl_up(w, off);
      if (t >= off) w += u;
    }
    wsum[t] = w;
  }
  __syncthreads();
  int waveBase = (wid == 0) ? 0 : wsum[wid - 1];
  int run = waveBase + v - sum;              // exclusive prefix of this thread's chunk
  for (int k = 0; k < EPT; ++k) {
    int i = base + k;
    if (i < N)       { offs[i] = run; run += hist[i]; }
    else if (i == N) { offs[N] = run; }
  }
}

// ---------------- bucket-scatter edge srcs into CSR order ----------------
__global__ void k_build(const int* __restrict__ src, const int* __restrict__ dst,
                        const int* __restrict__ offs, int* __restrict__ cursor,
                        int* __restrict__ csr_src, int E) {
  int e = blockIdx.x * blockDim.x + threadIdx.x;
  if (e < E) {
    int d = dst[e];
    int pos = offs[d] + atomicAdd(&cursor[d], 1);
    csr_src[pos] = src[e];
  }
}

// ---------------- simple LDS-tiled GEMM: C[M,NOUT] = A[M,K] @ W[K,NOUT] ----------------
template<int K, int NOUT, int ROWS>
__global__ void k_gemm(const float* __restrict__ A, const float* __restrict__ W,
                       float* __restrict__ C, int M) {
  __shared__ float As[ROWS * K];
  const int row0 = blockIdx.x * ROWS;
  const int tid  = threadIdx.x;
  for (int idx = tid; idx < ROWS * K; idx += NOUT) {
    int r = idx / K;
    As[idx] = (row0 + r < M) ? A[(size_t)row0 * K + idx] : 0.0f;
  }
  __syncthreads();
  float acc[ROWS];
#pragma unroll
  for (int r = 0; r < ROWS; ++r) acc[r] = 0.0f;
  for (int k = 0; k < K; ++k) {
    float w = W[k * NOUT + tid];
#pragma unroll
    for (int r = 0; r < ROWS; ++r) acc[r] = fmaf(As[r * K + k], w, acc[r]);
  }
#pragma unroll
  for (int r = 0; r < ROWS; ++r) {
    int m = row0 + r;
    if (m < M) C[(size_t)m * NOUT + tid] = acc[r];
  }
}

// ---------------- CSR gather: out[d] = sum_{s in N(d)} xw[s]*dinv[s]*dinv[d]
//                  + xw[d]*dinv[d]^2 + bias  (+optional relu) ----------------
// one wave per node; lanes span channels (VPL each).
template<int C, bool RELU>
__global__ void k_gather(const int* __restrict__ offs, const int* __restrict__ csr_src,
                         const float* __restrict__ dinv, const float* __restrict__ xw,
                         const float* __restrict__ bias, float* __restrict__ out, int N) {
  constexpr int VPL = C / 64;
  int wave = (int)((blockIdx.x * (size_t)blockDim.x + threadIdx.x) >> 6);
  int lane = threadIdx.x & 63;
  if (wave >= N) return;
  float dv = dinv[wave];
  int j0 = offs[wave], j1 = offs[wave + 1];
  float acc[VPL];
  const float* xself = xw + (size_t)wave * C + lane * VPL;
  float sc = dv * dv;
#pragma unroll
  for (int k = 0; k < VPL; ++k) acc[k] = xself[k] * sc;

  for (int base = j0; base < j1; base += 64) {
    int myj = base + lane;
    int s_l = 0; float dv_l = 0.0f;
    if (myj < j1) { s_l = csr_src[myj]; dv_l = dinv[s_l]; }
    int cnt = min(64, j1 - base);
    for (int k = 0; k < cnt; ++k) {
      int   s = __shfl(s_l, k);
      float c = __shfl(dv_l, k) * dv;
      const float* xs = xw + (size_t)s * C + lane * VPL;
      if constexpr (VPL == 4) {
        float4 v = *reinterpret_cast<const float4*>(xs);
        acc[0] = fmaf(v.x, c, acc[0]);
        acc[1] = fmaf(v.y, c, acc[1]);
        acc[2] = fmaf(v.z, c, acc[2]);
        acc[3] = fmaf(v.w, c, acc[3]);
      } else {
        float2 v = *reinterpret_cast<const float2*>(xs);
        acc[0] = fmaf(v.x, c, acc[0]);
        acc[1] = fmaf(v.y, c, acc[1]);
      }
    }
  }

  float* op = out + (size_t)wave * C + lane * VPL;
#pragma unroll
  for (int k = 0; k < VPL; ++k) {
    float v = acc[k] + bias[lane * VPL + k];
    op[k] = RELU ? fmaxf(v, 0.0f) : v;
  }
}

// ---------------- heads: node_x, p = emb@eW_top, q = emb@eW_bot (emb pre-biased) ----------------
__global__ void k_heads(const float* __restrict__ emb,
                        const float* __restrict__ nW, const float* __restrict__ nb,
                        const float* __restrict__ eW,
                        float* __restrict__ node_out,
                        float* __restrict__ p, float* __restrict__ q, int N) {
  int wave = (int)((blockIdx.x * (size_t)blockDim.x + threadIdx.x) >> 6);
  int lane = threadIdx.x & 63;
  if (wave >= N) return;
  int c0 = lane, c1 = lane + 64;
  float e0 = emb[(size_t)wave * H2 + c0];
  float e1 = emb[(size_t)wave * H2 + c1];
  float n0 = e0 * nW[c0 * 2 + 0] + e1 * nW[c1 * 2 + 0];
  float n1 = e0 * nW[c0 * 2 + 1] + e1 * nW[c1 * 2 + 1];
  float p0 = e0 * eW[c0 * 2 + 0] + e1 * eW[c1 * 2 + 0];
  float p1 = e0 * eW[c0 * 2 + 1] + e1 * eW[c1 * 2 + 1];
  float q0 = e0 * eW[(128 + c0) * 2 + 0] + e1 * eW[(128 + c1) * 2 + 0];
  float q1 = e0 * eW[(128 + c0) * 2 + 1] + e1 * eW[(128 + c1) * 2 + 1];
#pragma unroll
  for (int off = 32; off >= 1; off >>= 1) {
    n0 += __shfl_xor(n0, off);
    n1 += __shfl_xor(n1, off);
    p0 += __shfl_xor(p0, off);
    p1 += __shfl_xor(p1, off);
    q0 += __shfl_xor(q0, off);
    q1 += __shfl_xor(q1, off);
  }
  if (lane == 0) {
    node_out[(size_t)wave * 2 + 0] = n0 + nb[0];
    node_out[(size_t)wave * 2 + 1] = n1 + nb[1];
    p[(size_t)wave * 2 + 0] = p0;
    p[(size_t)wave * 2 + 1] = p1;
    q[(size_t)wave * 2 + 0] = q0;
    q[(size_t)wave * 2 + 1] = q1;
  }
}

// ---------------- edge output: out[e] = p[src] + q[dst] + eb ----------------
__global__ void k_edge(const int* __restrict__ src, const int* __restrict__ dst,
                       const float* __restrict__ p, const float* __restrict__ q,
                       const float* __restrict__ eb, float* __restrict__ eout, int E) {
  int e = blockIdx.x * blockDim.x + threadIdx.x;
  if (e < E) {
    int s = src[e], d = dst[e];
    float2 P = *reinterpret_cast<const float2*>(p + (size_t)s * 2);
    float2 Q = *reinterpret_cast<const float2*>(q + (size_t)d * 2);
    float2 o;
    o.x = P.x + Q.x + eb[0];
    o.y = P.y + Q.y + eb[1];
    *reinterpret_cast<float2*>(eout + (size_t)e * 2) = o;
  }
}

extern "C" void kernel_launch(void* const* d_in, const int* in_sizes, int n_in,
                              void* d_out, int out_size, void* d_ws, size_t ws_size,
                              hipStream_t stream) {
  const float* x   = (const float*)d_in[0];
  const int*   ei  = (const int*)d_in[1];
  const float* W1  = (const float*)d_in[2];
  const float* b1  = (const float*)d_in[3];
  const float* W2  = (const float*)d_in[4];
  const float* b2  = (const float*)d_in[5];
  const float* nW  = (const float*)d_in[6];
  const float* nb  = (const float*)d_in[7];
  const float* eW  = (const float*)d_in[8];
  const float* eb  = (const float*)d_in[9];

  const int N = in_sizes[0] / DIN;   // 50000
  const int E = in_sizes[1] / 2;     // 800000
  const int* src = ei;
  const int* dst = ei + E;

  float* ws   = (float*)d_ws;
  float* dinv = ws;                          // N
  float* p    = dinv + N;                    // 2N
  float* q    = p + 2 * (size_t)N;           // 2N
  float* xw1  = q + 2 * (size_t)N;           // 256N (later reused: xw2 | agg2)
  float* agg1 = xw1 + (size_t)H1 * N;        // 256N (h after bias+relu)
  float* xw2  = xw1;                         // 128N
  float* agg2 = xw1 + (size_t)H2 * N;        // 128N
  int*   hist = (int*)(agg1 + (size_t)H1 * N); // N   (reused as cursor)
  int*   offs = hist + N;                    // N+1
  int*   csr  = offs + N + 1;                // E

  float* node_out = (float*)d_out;                   // 2N
  float* edge_out = (float*)d_out + 2 * (size_t)N;   // 2E

  // ---- CSR build (shared by both layers) ----
  hipMemsetAsync(hist, 0, (size_t)N * sizeof(int), stream);
  k_hist<<<(E + 255) / 256, 256, 0, stream>>>(dst, hist, E);
  k_dinv<<<(N + 255) / 256, 256, 0, stream>>>(hist, dinv, N);
  k_scan<<<1, 1024, 0, stream>>>(hist, offs, N);
  hipMemsetAsync(hist, 0, (size_t)N * sizeof(int), stream);   // reuse as cursor
  k_build<<<(E + 255) / 256, 256, 0, stream>>>(src, dst, offs, hist, csr, E);

  // ---- layer 1 ----
  k_gemm<DIN, H1, 8><<<(N + 7) / 8, H1, 0, stream>>>(x, W1, xw1, N);
  k_gather<H1, true><<<(N + 3) / 4, 256, 0, stream>>>(offs, csr, dinv, xw1, b1, agg1, N);

  // ---- layer 2 ----
  k_gemm<H1, H2, 8><<<(N + 7) / 8, H2, 0, stream>>>(agg1, W2, xw2, N);
  k_gather<H2, false><<<(N + 3) / 4, 256, 0, stream>>>(offs, csr, dinv, xw2, b2, agg2, N);

  // ---- heads + edge output ----
  k_heads<<<(N + 3) / 4, 256, 0, stream>>>(agg2, nW, nb, eW, node_out, p, q, N);
  k_edge<<<(E + 255) / 256, 256, 0, stream>>>(src, dst, p, q, eb, edge_out, E);
}

// Round 3
// 421.909 us; speedup vs baseline: 8.4313x; 1.2430x over previous
//
#include <hip/hip_runtime.h>

static constexpr int DIN = 64;
static constexpr int H1  = 256;
static constexpr int H2  = 128;

using half8 = _Float16 __attribute__((ext_vector_type(8)));

// ---------------- degree histogram (int) ----------------
__global__ void k_hist(const int* __restrict__ dst, int* __restrict__ hist, int E) {
  int e = blockIdx.x * blockDim.x + threadIdx.x;
  if (e < E) atomicAdd(&hist[dst[e]], 1);
}

__global__ void k_dinv(const int* __restrict__ hist, float* __restrict__ dinv, int N) {
  int i = blockIdx.x * blockDim.x + threadIdx.x;
  if (i < N) dinv[i] = rsqrtf((float)hist[i] + 1.0f);   // +1 self-loop
}

// ---------------- exclusive scan of hist -> offs[0..N], single block 1024 thr ----------------
__global__ void k_scan(const int* __restrict__ hist, int* __restrict__ offs, int N) {
  __shared__ int wsum[16];
  const int t = threadIdx.x;
  const int EPT = (N + 1023) >> 10;
  const int base = t * EPT;
  int sum = 0;
  for (int k = 0; k < EPT; ++k) {
    int i = base + k;
    if (i < N) sum += hist[i];
  }
  int lane = t & 63, wid = t >> 6;
  int v = sum;
#pragma unroll
  for (int off = 1; off < 64; off <<= 1) {
    int u = __shfl_up(v, off);
    if (lane >= off) v += u;
  }
  if (lane == 63) wsum[wid] = v;
  __syncthreads();
  if (t < 16) {
    int w = wsum[t];
#pragma unroll
    for (int off = 1; off < 16; off <<= 1) {
      int u = __shfl_up(w, off);
      if (t >= off) w += u;
    }
    wsum[t] = w;
  }
  __syncthreads();
  int waveBase = (wid == 0) ? 0 : wsum[wid - 1];
  int run = waveBase + v - sum;
  for (int k = 0; k < EPT; ++k) {
    int i = base + k;
    if (i < N)       { offs[i] = run; run += hist[i]; }
    else if (i == N) { offs[N] = run; }
  }
}

// ---------------- bucket-scatter edge srcs into CSR order ----------------
__global__ void k_build(const int* __restrict__ src, const int* __restrict__ dst,
                        const int* __restrict__ offs, int* __restrict__ cursor,
                        int* __restrict__ csr_src, int E) {
  int e = blockIdx.x * blockDim.x + threadIdx.x;
  if (e < E) {
    int d = dst[e];
    int pos = offs[d] + atomicAdd(&cursor[d], 1);
    csr_src[pos] = src[e];
  }
}

// ---------------- LDS-tiled GEMM: C[M,NOUT] = A[M,K] @ W[K,NOUT], fp16 out ----------------
// blockDim.x == NOUT; each block does ROWS rows; fp32 accumulate.
template<int K, int NOUT, int ROWS, typename AT>
__global__ void k_gemm(const AT* __restrict__ A, const float* __restrict__ W,
                       _Float16* __restrict__ C, int M) {
  __shared__ float As[ROWS * K];
  const int row0 = blockIdx.x * ROWS;
  const int tid  = threadIdx.x;
  if (row0 + ROWS <= M) {
    if constexpr (sizeof(AT) == 2) {
      const half8* A8 = (const half8*)A;
      constexpr int NV = ROWS * K / 8;
      for (int v = tid; v < NV; v += NOUT) {
        half8 h = A8[(size_t)row0 * (K / 8) + v];
#pragma unroll
        for (int k = 0; k < 8; ++k) As[v * 8 + k] = (float)h[k];
      }
    } else {
      const float4* A4 = (const float4*)A;
      constexpr int NV = ROWS * K / 4;
      for (int v = tid; v < NV; v += NOUT) {
        float4 f = A4[(size_t)row0 * (K / 4) + v];
        As[v * 4 + 0] = f.x; As[v * 4 + 1] = f.y;
        As[v * 4 + 2] = f.z; As[v * 4 + 3] = f.w;
      }
    }
  } else {
    for (int idx = tid; idx < ROWS * K; idx += NOUT) {
      int r = idx / K;
      As[idx] = (row0 + r < M) ? (float)A[(size_t)row0 * K + idx] : 0.0f;
    }
  }
  __syncthreads();
  float acc[ROWS];
#pragma unroll
  for (int r = 0; r < ROWS; ++r) acc[r] = 0.0f;
  for (int k = 0; k < K; ++k) {
    float w = W[k * NOUT + tid];
#pragma unroll
    for (int r = 0; r < ROWS; ++r) acc[r] = fmaf(As[r * K + k], w, acc[r]);
  }
#pragma unroll
  for (int r = 0; r < ROWS; ++r) {
    int m = row0 + r;
    if (m < M) C[(size_t)m * NOUT + tid] = (_Float16)acc[r];
  }
}

// ---------------- CSR gather (fp16 payload, fp32 accumulate) ----------------
// out[d] = sum_{s in N(d)} xw[s]*dinv[s]*dinv[d] + xw[d]*dinv[d]^2 + bias (+relu)
// One wave per node. Lanes are split into 64*8/C groups; each group handles one
// edge per inner iteration with 16B half8 loads; final shfl_xor cross-group sum.
template<int C, bool RELU>
__global__ void k_gather(const int* __restrict__ offs, const int* __restrict__ csr_src,
                         const float* __restrict__ dinv, const _Float16* __restrict__ xw,
                         const float* __restrict__ bias, _Float16* __restrict__ out, int N) {
  constexpr int GSIZE = C / 8;      // lanes per edge-group (32 for H1, 16 for H2)
  constexpr int NE    = 64 / GSIZE; // edges per inner iteration (2 / 4)
  int wave = (int)((blockIdx.x * (size_t)blockDim.x + threadIdx.x) >> 6);
  int lane = threadIdx.x & 63;
  if (wave >= N) return;
  int group = lane / GSIZE;
  int sub   = lane % GSIZE;
  int ch0   = sub * 8;
  float dv = dinv[wave];
  int j0 = offs[wave], j1 = offs[wave + 1];

  float acc[8];
  if (group == 0) {
    half8 v = *(const half8*)(xw + (size_t)wave * C + ch0);
    float sc = dv * dv;
#pragma unroll
    for (int k = 0; k < 8; ++k) acc[k] = (float)v[k] * sc;
  } else {
#pragma unroll
    for (int k = 0; k < 8; ++k) acc[k] = 0.0f;
  }

  for (int base = j0; base < j1; base += 64) {
    int myj = base + lane;
    int s_l = 0; float dv_l = 0.0f;
    if (myj < j1) { s_l = csr_src[myj]; dv_l = dinv[s_l]; }
    int cnt = min(64, j1 - base);
    for (int k = 0; k < cnt; k += NE) {
      int idx = k + group;                  // <= 63 always; tail lanes have dv_l=0
      int   s = __shfl(s_l, idx);
      float c = __shfl(dv_l, idx) * dv;
      half8 v = *(const half8*)(xw + (size_t)s * C + ch0);
#pragma unroll
      for (int k2 = 0; k2 < 8; ++k2) acc[k2] = fmaf((float)v[k2], c, acc[k2]);
    }
  }

#pragma unroll
  for (int off = GSIZE; off < 64; off <<= 1) {
#pragma unroll
    for (int k = 0; k < 8; ++k) acc[k] += __shfl_xor(acc[k], off);
  }

  if (group == 0) {
    half8 o;
#pragma unroll
    for (int k = 0; k < 8; ++k) {
      float v = acc[k] + bias[ch0 + k];
      if (RELU) v = fmaxf(v, 0.0f);
      o[k] = (_Float16)v;
    }
    *(half8*)(out + (size_t)wave * C + ch0) = o;
  }
}

// ---------------- heads: node_x, p = emb@eW_top, q = emb@eW_bot (emb fp16, pre-biased) ----------------
__global__ void k_heads(const _Float16* __restrict__ emb,
                        const float* __restrict__ nW, const float* __restrict__ nb,
                        const float* __restrict__ eW,
                        float* __restrict__ node_out,
                        float* __restrict__ p, float* __restrict__ q, int N) {
  int wave = (int)((blockIdx.x * (size_t)blockDim.x + threadIdx.x) >> 6);
  int lane = threadIdx.x & 63;
  if (wave >= N) return;
  int c0 = lane, c1 = lane + 64;
  float e0 = (float)emb[(size_t)wave * H2 + c0];
  float e1 = (float)emb[(size_t)wave * H2 + c1];
  float n0 = e0 * nW[c0 * 2 + 0] + e1 * nW[c1 * 2 + 0];
  float n1 = e0 * nW[c0 * 2 + 1] + e1 * nW[c1 * 2 + 1];
  float p0 = e0 * eW[c0 * 2 + 0] + e1 * eW[c1 * 2 + 0];
  float p1 = e0 * eW[c0 * 2 + 1] + e1 * eW[c1 * 2 + 1];
  float q0 = e0 * eW[(128 + c0) * 2 + 0] + e1 * eW[(128 + c1) * 2 + 0];
  float q1 = e0 * eW[(128 + c0) * 2 + 1] + e1 * eW[(128 + c1) * 2 + 1];
#pragma unroll
  for (int off = 32; off >= 1; off >>= 1) {
    n0 += __shfl_xor(n0, off);
    n1 += __shfl_xor(n1, off);
    p0 += __shfl_xor(p0, off);
    p1 += __shfl_xor(p1, off);
    q0 += __shfl_xor(q0, off);
    q1 += __shfl_xor(q1, off);
  }
  if (lane == 0) {
    node_out[(size_t)wave * 2 + 0] = n0 + nb[0];
    node_out[(size_t)wave * 2 + 1] = n1 + nb[1];
    p[(size_t)wave * 2 + 0] = p0;
    p[(size_t)wave * 2 + 1] = p1;
    q[(size_t)wave * 2 + 0] = q0;
    q[(size_t)wave * 2 + 1] = q1;
  }
}

// ---------------- edge output: out[e] = p[src] + q[dst] + eb ----------------
__global__ void k_edge(const int* __restrict__ src, const int* __restrict__ dst,
                       const float* __restrict__ p, const float* __restrict__ q,
                       const float* __restrict__ eb, float* __restrict__ eout, int E) {
  int e = blockIdx.x * blockDim.x + threadIdx.x;
  if (e < E) {
    int s = src[e], d = dst[e];
    float2 P = *reinterpret_cast<const float2*>(p + (size_t)s * 2);
    float2 Q = *reinterpret_cast<const float2*>(q + (size_t)d * 2);
    float2 o;
    o.x = P.x + Q.x + eb[0];
    o.y = P.y + Q.y + eb[1];
    *reinterpret_cast<float2*>(eout + (size_t)e * 2) = o;
  }
}

extern "C" void kernel_launch(void* const* d_in, const int* in_sizes, int n_in,
                              void* d_out, int out_size, void* d_ws, size_t ws_size,
                              hipStream_t stream) {
  const float* x   = (const float*)d_in[0];
  const int*   ei  = (const int*)d_in[1];
  const float* W1  = (const float*)d_in[2];
  const float* b1  = (const float*)d_in[3];
  const float* W2  = (const float*)d_in[4];
  const float* b2  = (const float*)d_in[5];
  const float* nW  = (const float*)d_in[6];
  const float* nb  = (const float*)d_in[7];
  const float* eW  = (const float*)d_in[8];
  const float* eb  = (const float*)d_in[9];

  const int N = in_sizes[0] / DIN;   // 50000
  const int E = in_sizes[1] / 2;     // 800000
  const int* src = ei;
  const int* dst = ei + E;

  float* ws   = (float*)d_ws;
  float* dinv = ws;                              // N
  float* p    = dinv + N;                        // 2N
  float* q    = p + 2 * (size_t)N;               // 2N
  _Float16* xw1h  = (_Float16*)(q + 2 * (size_t)N);  // 256N halves
  _Float16* agg1h = xw1h + (size_t)H1 * N;           // 256N halves (h, post-relu)
  _Float16* xw2h  = agg1h + (size_t)H1 * N;          // 128N halves
  _Float16* agg2h = xw2h + (size_t)H2 * N;           // 128N halves (emb, pre-biased)
  int* hist = (int*)(agg2h + (size_t)H2 * N);        // N (reused as cursor)
  int* offs = hist + N;                              // N+1
  int* csr  = offs + N + 1;                          // E

  float* node_out = (float*)d_out;                   // 2N
  float* edge_out = (float*)d_out + 2 * (size_t)N;   // 2E

  // ---- CSR build (shared by both layers) ----
  hipMemsetAsync(hist, 0, (size_t)N * sizeof(int), stream);
  k_hist<<<(E + 255) / 256, 256, 0, stream>>>(dst, hist, E);
  k_dinv<<<(N + 255) / 256, 256, 0, stream>>>(hist, dinv, N);
  k_scan<<<1, 1024, 0, stream>>>(hist, offs, N);
  hipMemsetAsync(hist, 0, (size_t)N * sizeof(int), stream);   // reuse as cursor
  k_build<<<(E + 255) / 256, 256, 0, stream>>>(src, dst, offs, hist, csr, E);

  // ---- layer 1 ----
  k_gemm<DIN, H1, 16, float><<<(N + 15) / 16, H1, 0, stream>>>(x, W1, xw1h, N);
  k_gather<H1, true><<<(N + 3) / 4, 256, 0, stream>>>(offs, csr, dinv, xw1h, b1, agg1h, N);

  // ---- layer 2 ----
  k_gemm<H1, H2, 16, _Float16><<<(N + 15) / 16, H2, 0, stream>>>(agg1h, W2, xw2h, N);
  k_gather<H2, false><<<(N + 3) / 4, 256, 0, stream>>>(offs, csr, dinv, xw2h, b2, agg2h, N);

  // ---- heads + edge output ----
  k_heads<<<(N + 3) / 4, 256, 0, stream>>>(agg2h, nW, nb, eW, node_out, p, q, N);
  k_edge<<<(E + 255) / 256, 256, 0, stream>>>(src, dst, p, q, eb, edge_out, E);
}

// Round 4
// 298.778 us; speedup vs baseline: 11.9060x; 1.4121x over previous
//
#include <hip/hip_runtime.h>

static constexpr int DIN = 64;
static constexpr int H1  = 256;
static constexpr int H2  = 128;

using half8 = _Float16 __attribute__((ext_vector_type(8)));

// ---------------- degree histogram (int) ----------------
__global__ void k_hist(const int* __restrict__ dst, int* __restrict__ hist, int E) {
  int e = blockIdx.x * blockDim.x + threadIdx.x;
  if (e < E) atomicAdd(&hist[dst[e]], 1);
}

__global__ void k_dinv(const int* __restrict__ hist, float* __restrict__ dinv, int N) {
  int i = blockIdx.x * blockDim.x + threadIdx.x;
  if (i < N) dinv[i] = rsqrtf((float)hist[i] + 1.0f);   // +1 self-loop
}

// ---------------- hierarchical exclusive scan: hist[N] -> offs[N+1] ----------------
// phase 1: per-block (1024 elems) local exclusive scan + block sums
__global__ void k_scan1(const int* __restrict__ hist, int* __restrict__ offs,
                        int* __restrict__ bsum, int N) {
  __shared__ int ws[4];
  const int t = threadIdx.x;
  const int base = blockIdx.x * 1024 + t * 4;
  int4 v = make_int4(0, 0, 0, 0);
  if (base + 3 < N) v = *(const int4*)(hist + base);
  else {
    if (base + 0 < N) v.x = hist[base + 0];
    if (base + 1 < N) v.y = hist[base + 1];
    if (base + 2 < N) v.z = hist[base + 2];
    if (base + 3 < N) v.w = hist[base + 3];
  }
  int tsum = v.x + v.y + v.z + v.w;
  int lane = t & 63, wid = t >> 6;
  int incl = tsum;
#pragma unroll
  for (int off = 1; off < 64; off <<= 1) {
    int u = __shfl_up(incl, off);
    if (lane >= off) incl += u;
  }
  if (lane == 63) ws[wid] = incl;
  __syncthreads();
  int wbase = 0;
  for (int w = 0; w < wid; ++w) wbase += ws[w];
  int excl = wbase + incl - tsum;
  int4 o;
  o.x = excl;
  o.y = excl + v.x;
  o.z = excl + v.x + v.y;
  o.w = excl + v.x + v.y + v.z;
  if (base + 3 < N) *(int4*)(offs + base) = o;
  else {
    if (base + 0 < N) offs[base + 0] = o.x;
    if (base + 1 < N) offs[base + 1] = o.y;
    if (base + 2 < N) offs[base + 2] = o.z;
    if (base + 3 < N) offs[base + 3] = o.w;
  }
  if (t == 255) bsum[blockIdx.x] = wbase + incl;   // block total
}

// phase 2: scan block sums (nb <= 64), set offs[N] = E
__global__ void k_scan2(int* __restrict__ bsum, int* __restrict__ offs,
                        int nb, int N, int E) {
  int t = threadIdx.x;   // 64 threads
  int v = (t < nb) ? bsum[t] : 0;
  int incl = v;
#pragma unroll
  for (int off = 1; off < 64; off <<= 1) {
    int u = __shfl_up(incl, off);
    if (t >= off) incl += u;
  }
  if (t < nb) bsum[t] = incl - v;   // exclusive base per block
  if (t == 0) offs[N] = E;
}

// phase 3: add block bases
__global__ void k_scan3(int* __restrict__ offs, const int* __restrict__ bsum, int N) {
  if (blockIdx.x == 0) return;
  int b = bsum[blockIdx.x];
  int base = blockIdx.x * 1024 + threadIdx.x * 4;
  if (base + 3 < N) {
    int4 v = *(int4*)(offs + base);
    v.x += b; v.y += b; v.z += b; v.w += b;
    *(int4*)(offs + base) = v;
  } else {
    for (int k = 0; k < 4; ++k) if (base + k < N) offs[base + k] += b;
  }
}

// ---------------- bucket-scatter edge srcs into CSR order ----------------
__global__ void k_build(const int* __restrict__ src, const int* __restrict__ dst,
                        const int* __restrict__ offs, int* __restrict__ cursor,
                        int* __restrict__ csr_src, int E) {
  int e = blockIdx.x * blockDim.x + threadIdx.x;
  if (e < E) {
    int d = dst[e];
    int pos = offs[d] + atomicAdd(&cursor[d], 1);
    csr_src[pos] = src[e];
  }
}

// ---------------- cast fp32 -> fp16, vector 8 ----------------
__global__ void k_cast(const float* __restrict__ x, _Float16* __restrict__ xh, int nvec8) {
  int i = blockIdx.x * blockDim.x + threadIdx.x;
  if (i < nvec8) {
    const float4* x4 = (const float4*)x;
    float4 a = x4[i * 2 + 0];
    float4 b = x4[i * 2 + 1];
    half8 h;
    h[0] = (_Float16)a.x; h[1] = (_Float16)a.y; h[2] = (_Float16)a.z; h[3] = (_Float16)a.w;
    h[4] = (_Float16)b.x; h[5] = (_Float16)b.y; h[6] = (_Float16)b.z; h[7] = (_Float16)b.w;
    *(half8*)(xh + (size_t)i * 8) = h;
  }
}

// ---------------- LDS-tiled GEMM: C[M,NOUT] = A[M,K] @ W[K,NOUT], fp16 in/out ----------------
template<int K, int NOUT, int ROWS, bool BIAS, bool RELU>
__global__ void k_gemm(const _Float16* __restrict__ A, const float* __restrict__ W,
                       const float* __restrict__ bias, _Float16* __restrict__ C, int M) {
  __shared__ float As[ROWS * K];
  const int row0 = blockIdx.x * ROWS;
  const int tid  = threadIdx.x;
  if (row0 + ROWS <= M) {
    const half8* A8 = (const half8*)A;
    constexpr int NV = ROWS * K / 8;
    for (int v = tid; v < NV; v += NOUT) {
      half8 h = A8[(size_t)row0 * (K / 8) + v];
#pragma unroll
      for (int k = 0; k < 8; ++k) As[v * 8 + k] = (float)h[k];
    }
  } else {
    for (int idx = tid; idx < ROWS * K; idx += NOUT) {
      int r = idx / K;
      As[idx] = (row0 + r < M) ? (float)A[(size_t)row0 * K + idx] : 0.0f;
    }
  }
  __syncthreads();
  float acc[ROWS];
#pragma unroll
  for (int r = 0; r < ROWS; ++r) acc[r] = 0.0f;
  for (int k = 0; k < K; ++k) {
    float w = W[k * NOUT + tid];
#pragma unroll
    for (int r = 0; r < ROWS; ++r) acc[r] = fmaf(As[r * K + k], w, acc[r]);
  }
  float b = BIAS ? bias[tid] : 0.0f;
#pragma unroll
  for (int r = 0; r < ROWS; ++r) {
    int m = row0 + r;
    if (m < M) {
      float v = acc[r] + b;
      if (RELU) v = fmaxf(v, 0.0f);
      C[(size_t)m * NOUT + tid] = (_Float16)v;
    }
  }
}

// ---------------- CSR gather (fp16 payload, fp32 accumulate) ----------------
// out[d] = sum_{s in N(d)} xw[s]*dinv[s]*dinv[d] + xw[d]*dinv[d]^2 (+bias)
// One wave per node; 64*8/C lane-groups each handle one edge/iter via half8 loads.
template<int C, bool BIAS>
__global__ void k_gather(const int* __restrict__ offs, const int* __restrict__ csr_src,
                         const float* __restrict__ dinv, const _Float16* __restrict__ xw,
                         const float* __restrict__ bias, _Float16* __restrict__ out, int N) {
  constexpr int GSIZE = C / 8;      // lanes per edge-group (8 for C=64, 16 for C=128)
  constexpr int NE    = 64 / GSIZE; // edges per inner iteration
  int wave = (int)((blockIdx.x * (size_t)blockDim.x + threadIdx.x) >> 6);
  int lane = threadIdx.x & 63;
  if (wave >= N) return;
  int group = lane / GSIZE;
  int sub   = lane % GSIZE;
  int ch0   = sub * 8;
  float dv = dinv[wave];
  int j0 = offs[wave], j1 = offs[wave + 1];

  float acc[8];
  if (group == 0) {
    half8 v = *(const half8*)(xw + (size_t)wave * C + ch0);
    float sc = dv * dv;
#pragma unroll
    for (int k = 0; k < 8; ++k) acc[k] = (float)v[k] * sc;
  } else {
#pragma unroll
    for (int k = 0; k < 8; ++k) acc[k] = 0.0f;
  }

  for (int base = j0; base < j1; base += 64) {
    int myj = base + lane;
    int s_l = 0; float dv_l = 0.0f;
    if (myj < j1) { s_l = csr_src[myj]; dv_l = dinv[s_l]; }
    int cnt = min(64, j1 - base);
    for (int k = 0; k < cnt; k += NE) {
      int idx = k + group;                  // <= 63; overflow lanes carry dv_l=0
      int   s = __shfl(s_l, idx);
      float c = __shfl(dv_l, idx) * dv;
      half8 v = *(const half8*)(xw + (size_t)s * C + ch0);
#pragma unroll
      for (int k2 = 0; k2 < 8; ++k2) acc[k2] = fmaf((float)v[k2], c, acc[k2]);
    }
  }

#pragma unroll
  for (int off = GSIZE; off < 64; off <<= 1) {
#pragma unroll
    for (int k = 0; k < 8; ++k) acc[k] += __shfl_xor(acc[k], off);
  }

  if (group == 0) {
    half8 o;
#pragma unroll
    for (int k = 0; k < 8; ++k) {
      float v = acc[k] + (BIAS ? bias[ch0 + k] : 0.0f);
      o[k] = (_Float16)v;
    }
    *(half8*)(out + (size_t)wave * C + ch0) = o;
  }
}

// ---------------- heads: node_x, p = emb@eW_top, q = emb@eW_bot (emb fp16, pre-biased) ----------------
__global__ void k_heads(const _Float16* __restrict__ emb,
                        const float* __restrict__ nW, const float* __restrict__ nb,
                        const float* __restrict__ eW,
                        float* __restrict__ node_out,
                        float* __restrict__ p, float* __restrict__ q, int N) {
  int wave = (int)((blockIdx.x * (size_t)blockDim.x + threadIdx.x) >> 6);
  int lane = threadIdx.x & 63;
  if (wave >= N) return;
  int c0 = lane, c1 = lane + 64;
  float e0 = (float)emb[(size_t)wave * H2 + c0];
  float e1 = (float)emb[(size_t)wave * H2 + c1];
  float n0 = e0 * nW[c0 * 2 + 0] + e1 * nW[c1 * 2 + 0];
  float n1 = e0 * nW[c0 * 2 + 1] + e1 * nW[c1 * 2 + 1];
  float p0 = e0 * eW[c0 * 2 + 0] + e1 * eW[c1 * 2 + 0];
  float p1 = e0 * eW[c0 * 2 + 1] + e1 * eW[c1 * 2 + 1];
  float q0 = e0 * eW[(128 + c0) * 2 + 0] + e1 * eW[(128 + c1) * 2 + 0];
  float q1 = e0 * eW[(128 + c0) * 2 + 1] + e1 * eW[(128 + c1) * 2 + 1];
#pragma unroll
  for (int off = 32; off >= 1; off >>= 1) {
    n0 += __shfl_xor(n0, off);
    n1 += __shfl_xor(n1, off);
    p0 += __shfl_xor(p0, off);
    p1 += __shfl_xor(p1, off);
    q0 += __shfl_xor(q0, off);
    q1 += __shfl_xor(q1, off);
  }
  if (lane == 0) {
    node_out[(size_t)wave * 2 + 0] = n0 + nb[0];
    node_out[(size_t)wave * 2 + 1] = n1 + nb[1];
    p[(size_t)wave * 2 + 0] = p0;
    p[(size_t)wave * 2 + 1] = p1;
    q[(size_t)wave * 2 + 0] = q0;
    q[(size_t)wave * 2 + 1] = q1;
  }
}

// ---------------- edge output: out[e] = p[src] + q[dst] + eb ----------------
__global__ void k_edge(const int* __restrict__ src, const int* __restrict__ dst,
                       const float* __restrict__ p, const float* __restrict__ q,
                       const float* __restrict__ eb, float* __restrict__ eout, int E) {
  int e = blockIdx.x * blockDim.x + threadIdx.x;
  if (e < E) {
    int s = src[e], d = dst[e];
    float2 P = *reinterpret_cast<const float2*>(p + (size_t)s * 2);
    float2 Q = *reinterpret_cast<const float2*>(q + (size_t)d * 2);
    float2 o;
    o.x = P.x + Q.x + eb[0];
    o.y = P.y + Q.y + eb[1];
    *reinterpret_cast<float2*>(eout + (size_t)e * 2) = o;
  }
}

extern "C" void kernel_launch(void* const* d_in, const int* in_sizes, int n_in,
                              void* d_out, int out_size, void* d_ws, size_t ws_size,
                              hipStream_t stream) {
  const float* x   = (const float*)d_in[0];
  const int*   ei  = (const int*)d_in[1];
  const float* W1  = (const float*)d_in[2];
  const float* b1  = (const float*)d_in[3];
  const float* W2  = (const float*)d_in[4];
  const float* b2  = (const float*)d_in[5];
  const float* nW  = (const float*)d_in[6];
  const float* nb  = (const float*)d_in[7];
  const float* eW  = (const float*)d_in[8];
  const float* eb  = (const float*)d_in[9];

  const int N = in_sizes[0] / DIN;   // 50000
  const int E = in_sizes[1] / 2;     // 800000
  const int* src = ei;
  const int* dst = ei + E;

  float* ws   = (float*)d_ws;
  float* dinv = ws;                              // N
  float* p    = dinv + N;                        // 2N
  float* q    = p + 2 * (size_t)N;               // 2N
  _Float16* xh    = (_Float16*)(q + 2 * (size_t)N);  // 64N  (x in fp16)
  _Float16* aggxh = xh + (size_t)DIN * N;            // 64N  (aggregated x)
  _Float16* h     = aggxh + (size_t)DIN * N;         // 256N (post relu)
  _Float16* xw2h  = h + (size_t)H1 * N;              // 128N
  _Float16* emb   = xw2h + (size_t)H2 * N;           // 128N (pre-biased emb)
  int* hist = (int*)(emb + (size_t)H2 * N);          // N (reused as cursor)
  int* offs = hist + N;                              // N+1
  int* bsum = offs + N + 1;                          // 64
  int* csr  = bsum + 64;                             // E

  float* node_out = (float*)d_out;                   // 2N
  float* edge_out = (float*)d_out + 2 * (size_t)N;   // 2E

  const int nb_blk = (N + 1023) / 1024;              // 49

  // ---- CSR build (shared by both layers) ----
  hipMemsetAsync(hist, 0, (size_t)N * sizeof(int), stream);
  k_hist<<<(E + 255) / 256, 256, 0, stream>>>(dst, hist, E);
  k_dinv<<<(N + 255) / 256, 256, 0, stream>>>(hist, dinv, N);
  k_scan1<<<nb_blk, 256, 0, stream>>>(hist, offs, bsum, N);
  k_scan2<<<1, 64, 0, stream>>>(bsum, offs, nb_blk, N, E);
  k_scan3<<<nb_blk, 256, 0, stream>>>(offs, bsum, N);
  hipMemsetAsync(hist, 0, (size_t)N * sizeof(int), stream);   // reuse as cursor
  k_build<<<(E + 255) / 256, 256, 0, stream>>>(src, dst, offs, hist, csr, E);

  // ---- layer 1: aggregate-then-transform (DIN=64 < H1=256) ----
  k_cast<<<((N * DIN / 8) + 255) / 256, 256, 0, stream>>>(x, xh, N * DIN / 8);
  k_gather<DIN, false><<<(N + 3) / 4, 256, 0, stream>>>(offs, csr, dinv, xh, nullptr, aggxh, N);
  k_gemm<DIN, H1, 16, true, true><<<(N + 15) / 16, H1, 0, stream>>>(aggxh, W1, b1, h, N);

  // ---- layer 2: transform-then-aggregate (H2=128 < H1=256) ----
  k_gemm<H1, H2, 16, false, false><<<(N + 15) / 16, H2, 0, stream>>>(h, W2, nullptr, xw2h, N);
  k_gather<H2, true><<<(N + 3) / 4, 256, 0, stream>>>(offs, csr, dinv, xw2h, b2, emb, N);

  // ---- heads + edge output ----
  k_heads<<<(N + 3) / 4, 256, 0, stream>>>(emb, nW, nb, eW, node_out, p, q, N);
  k_edge<<<(E + 255) / 256, 256, 0, stream>>>(src, dst, p, q, eb, edge_out, E);
}

// Round 5
// 259.877 us; speedup vs baseline: 13.6882x; 1.1497x over previous
//
#include <hip/hip_runtime.h>

static constexpr int DIN = 64;
static constexpr int H1  = 256;
static constexpr int H2  = 128;

using half8 = _Float16 __attribute__((ext_vector_type(8)));
using f32x4 = float __attribute__((ext_vector_type(4)));

// ---------------- degree histogram (int) ----------------
__global__ void k_hist(const int* __restrict__ dst, int* __restrict__ hist, int E) {
  int e = blockIdx.x * blockDim.x + threadIdx.x;
  if (e < E) atomicAdd(&hist[dst[e]], 1);
}

__global__ void k_dinv(const int* __restrict__ hist, float* __restrict__ dinv, int N) {
  int i = blockIdx.x * blockDim.x + threadIdx.x;
  if (i < N) dinv[i] = rsqrtf((float)hist[i] + 1.0f);   // +1 self-loop
}

// ---------------- hierarchical exclusive scan: hist[N] -> offs[N+1] ----------------
__global__ void k_scan1(const int* __restrict__ hist, int* __restrict__ offs,
                        int* __restrict__ bsum, int N) {
  __shared__ int ws[4];
  const int t = threadIdx.x;
  const int base = blockIdx.x * 1024 + t * 4;
  int4 v = make_int4(0, 0, 0, 0);
  if (base + 3 < N) v = *(const int4*)(hist + base);
  else {
    if (base + 0 < N) v.x = hist[base + 0];
    if (base + 1 < N) v.y = hist[base + 1];
    if (base + 2 < N) v.z = hist[base + 2];
    if (base + 3 < N) v.w = hist[base + 3];
  }
  int tsum = v.x + v.y + v.z + v.w;
  int lane = t & 63, wid = t >> 6;
  int incl = tsum;
#pragma unroll
  for (int off = 1; off < 64; off <<= 1) {
    int u = __shfl_up(incl, off);
    if (lane >= off) incl += u;
  }
  if (lane == 63) ws[wid] = incl;
  __syncthreads();
  int wbase = 0;
  for (int w = 0; w < wid; ++w) wbase += ws[w];
  int excl = wbase + incl - tsum;
  int4 o;
  o.x = excl;
  o.y = excl + v.x;
  o.z = excl + v.x + v.y;
  o.w = excl + v.x + v.y + v.z;
  if (base + 3 < N) *(int4*)(offs + base) = o;
  else {
    if (base + 0 < N) offs[base + 0] = o.x;
    if (base + 1 < N) offs[base + 1] = o.y;
    if (base + 2 < N) offs[base + 2] = o.z;
    if (base + 3 < N) offs[base + 3] = o.w;
  }
  if (t == 255) bsum[blockIdx.x] = wbase + incl;
}

__global__ void k_scan2(int* __restrict__ bsum, int* __restrict__ offs,
                        int nb, int N, int E) {
  int t = threadIdx.x;
  int v = (t < nb) ? bsum[t] : 0;
  int incl = v;
#pragma unroll
  for (int off = 1; off < 64; off <<= 1) {
    int u = __shfl_up(incl, off);
    if (t >= off) incl += u;
  }
  if (t < nb) bsum[t] = incl - v;
  if (t == 0) offs[N] = E;
}

__global__ void k_scan3(int* __restrict__ offs, const int* __restrict__ bsum, int N) {
  if (blockIdx.x == 0) return;
  int b = bsum[blockIdx.x];
  int base = blockIdx.x * 1024 + threadIdx.x * 4;
  if (base + 3 < N) {
    int4 v = *(int4*)(offs + base);
    v.x += b; v.y += b; v.z += b; v.w += b;
    *(int4*)(offs + base) = v;
  } else {
    for (int k = 0; k < 4; ++k) if (base + k < N) offs[base + k] += b;
  }
}

// ---------------- bucket-scatter edge srcs into CSR order ----------------
__global__ void k_build(const int* __restrict__ src, const int* __restrict__ dst,
                        const int* __restrict__ offs, int* __restrict__ cursor,
                        int* __restrict__ csr_src, int E) {
  int e = blockIdx.x * blockDim.x + threadIdx.x;
  if (e < E) {
    int d = dst[e];
    int pos = offs[d] + atomicAdd(&cursor[d], 1);
    csr_src[pos] = src[e];
  }
}

// ---------------- cast fp32 -> fp16, vector 8 ----------------
__global__ void k_cast(const float* __restrict__ x, _Float16* __restrict__ xh, int nvec8) {
  int i = blockIdx.x * blockDim.x + threadIdx.x;
  if (i < nvec8) {
    const float4* x4 = (const float4*)x;
    float4 a = x4[i * 2 + 0];
    float4 b = x4[i * 2 + 1];
    half8 h;
    h[0] = (_Float16)a.x; h[1] = (_Float16)a.y; h[2] = (_Float16)a.z; h[3] = (_Float16)a.w;
    h[4] = (_Float16)b.x; h[5] = (_Float16)b.y; h[6] = (_Float16)b.z; h[7] = (_Float16)b.w;
    *(half8*)(xh + (size_t)i * 8) = h;
  }
}

// ---------------- W[K][NOUT] fp32 -> B-fragment-ordered fp16 table ----------------
// Wf element i: j=i&7, lane=(i>>3)&63, t=(i>>9)%(K/32), c=(i>>9)/(K/32)
// holds W[t*32 + (lane>>4)*8 + j][c*16 + (lane&15)]
template<int K, int NOUT>
__global__ void k_wfrag(const float* __restrict__ W, _Float16* __restrict__ Wf) {
  int i = blockIdx.x * blockDim.x + threadIdx.x;
  if (i >= K * NOUT) return;
  int j    = i & 7;
  int lane = (i >> 3) & 63;
  int rest = i >> 9;
  int t    = rest % (K / 32);
  int c    = rest / (K / 32);
  int k    = t * 32 + (lane >> 4) * 8 + j;
  int col  = c * 16 + (lane & 15);
  Wf[i] = (_Float16)W[k * NOUT + col];
}

// ---------------- MFMA GEMM: C[M,NOUT] = A[M,K] @ W[K,NOUT] ----------------
// 256 thr = 4 waves; each wave: 32 rows x NOUT cols, fp32 acc, no LDS.
template<int K, int NOUT, bool BIAS, bool RELU>
__global__ void k_mgemm(const _Float16* __restrict__ A, const _Float16* __restrict__ Wf,
                        const float* __restrict__ bias, _Float16* __restrict__ C, int M) {
  constexpr int NC = NOUT / 16;   // col blocks
  constexpr int NT = K / 32;      // k steps
  const int wave = threadIdx.x >> 6;
  const int lane = threadIdx.x & 63;
  const int rowbase = blockIdx.x * 128 + wave * 32;
  if (rowbase >= M) return;
  const int r  = lane & 15;
  const int kb = lane >> 4;
  int row0 = rowbase + r;       if (row0 >= M) row0 = M - 1;
  int row1 = rowbase + 16 + r;  if (row1 >= M) row1 = M - 1;
  const _Float16* a0p = A + (size_t)row0 * K + kb * 8;
  const _Float16* a1p = A + (size_t)row1 * K + kb * 8;

  f32x4 acc[2][NC];
#pragma unroll
  for (int rb = 0; rb < 2; ++rb)
#pragma unroll
    for (int c = 0; c < NC; ++c) acc[rb][c] = (f32x4)0.0f;

#pragma unroll
  for (int t = 0; t < NT; ++t) {
    half8 a0 = *(const half8*)(a0p + t * 32);
    half8 a1 = *(const half8*)(a1p + t * 32);
#pragma unroll
    for (int c = 0; c < NC; ++c) {
      half8 bf = ((const half8*)Wf)[(size_t)(c * NT + t) * 64 + lane];
      acc[0][c] = __builtin_amdgcn_mfma_f32_16x16x32_f16(a0, bf, acc[0][c], 0, 0, 0);
      acc[1][c] = __builtin_amdgcn_mfma_f32_16x16x32_f16(a1, bf, acc[1][c], 0, 0, 0);
    }
  }

  // C/D layout: col = lane&15, row = (lane>>4)*4 + reg
#pragma unroll
  for (int rb = 0; rb < 2; ++rb) {
    int growbase = rowbase + rb * 16 + kb * 4;
#pragma unroll
    for (int c = 0; c < NC; ++c) {
      int col = c * 16 + r;
      float bv = BIAS ? bias[col] : 0.0f;
#pragma unroll
      for (int j = 0; j < 4; ++j) {
        int grow = growbase + j;
        if (grow < M) {
          float v = acc[rb][c][j] + bv;
          if (RELU) v = fmaxf(v, 0.0f);
          C[(size_t)grow * NOUT + col] = (_Float16)v;
        }
      }
    }
  }
}

// ---------------- CSR gather (fp16 payload, fp32 accumulate) ----------------
template<int C, bool BIAS>
__global__ void k_gather(const int* __restrict__ offs, const int* __restrict__ csr_src,
                         const float* __restrict__ dinv, const _Float16* __restrict__ xw,
                         const float* __restrict__ bias, _Float16* __restrict__ out, int N) {
  constexpr int GSIZE = C / 8;
  constexpr int NE    = 64 / GSIZE;
  int wave = (int)((blockIdx.x * (size_t)blockDim.x + threadIdx.x) >> 6);
  int lane = threadIdx.x & 63;
  if (wave >= N) return;
  int group = lane / GSIZE;
  int sub   = lane % GSIZE;
  int ch0   = sub * 8;
  float dv = dinv[wave];
  int j0 = offs[wave], j1 = offs[wave + 1];

  float acc[8];
  if (group == 0) {
    half8 v = *(const half8*)(xw + (size_t)wave * C + ch0);
    float sc = dv * dv;
#pragma unroll
    for (int k = 0; k < 8; ++k) acc[k] = (float)v[k] * sc;
  } else {
#pragma unroll
    for (int k = 0; k < 8; ++k) acc[k] = 0.0f;
  }

  for (int base = j0; base < j1; base += 64) {
    int myj = base + lane;
    int s_l = 0; float dv_l = 0.0f;
    if (myj < j1) { s_l = csr_src[myj]; dv_l = dinv[s_l]; }
    int cnt = min(64, j1 - base);
    for (int k = 0; k < cnt; k += NE) {
      int idx = k + group;
      int   s = __shfl(s_l, idx);
      float c = __shfl(dv_l, idx) * dv;
      half8 v = *(const half8*)(xw + (size_t)s * C + ch0);
#pragma unroll
      for (int k2 = 0; k2 < 8; ++k2) acc[k2] = fmaf((float)v[k2], c, acc[k2]);
    }
  }

#pragma unroll
  for (int off = GSIZE; off < 64; off <<= 1) {
#pragma unroll
    for (int k = 0; k < 8; ++k) acc[k] += __shfl_xor(acc[k], off);
  }

  if (group == 0) {
    half8 o;
#pragma unroll
    for (int k = 0; k < 8; ++k) {
      float v = acc[k] + (BIAS ? bias[ch0 + k] : 0.0f);
      o[k] = (_Float16)v;
    }
    *(half8*)(out + (size_t)wave * C + ch0) = o;
  }
}

// ---------------- heads ----------------
__global__ void k_heads(const _Float16* __restrict__ emb,
                        const float* __restrict__ nW, const float* __restrict__ nb,
                        const float* __restrict__ eW,
                        float* __restrict__ node_out,
                        float* __restrict__ p, float* __restrict__ q, int N) {
  int wave = (int)((blockIdx.x * (size_t)blockDim.x + threadIdx.x) >> 6);
  int lane = threadIdx.x & 63;
  if (wave >= N) return;
  int c0 = lane, c1 = lane + 64;
  float e0 = (float)emb[(size_t)wave * H2 + c0];
  float e1 = (float)emb[(size_t)wave * H2 + c1];
  float n0 = e0 * nW[c0 * 2 + 0] + e1 * nW[c1 * 2 + 0];
  float n1 = e0 * nW[c0 * 2 + 1] + e1 * nW[c1 * 2 + 1];
  float p0 = e0 * eW[c0 * 2 + 0] + e1 * eW[c1 * 2 + 0];
  float p1 = e0 * eW[c0 * 2 + 1] + e1 * eW[c1 * 2 + 1];
  float q0 = e0 * eW[(128 + c0) * 2 + 0] + e1 * eW[(128 + c1) * 2 + 0];
  float q1 = e0 * eW[(128 + c0) * 2 + 1] + e1 * eW[(128 + c1) * 2 + 1];
#pragma unroll
  for (int off = 32; off >= 1; off >>= 1) {
    n0 += __shfl_xor(n0, off);
    n1 += __shfl_xor(n1, off);
    p0 += __shfl_xor(p0, off);
    p1 += __shfl_xor(p1, off);
    q0 += __shfl_xor(q0, off);
    q1 += __shfl_xor(q1, off);
  }
  if (lane == 0) {
    node_out[(size_t)wave * 2 + 0] = n0 + nb[0];
    node_out[(size_t)wave * 2 + 1] = n1 + nb[1];
    p[(size_t)wave * 2 + 0] = p0;
    p[(size_t)wave * 2 + 1] = p1;
    q[(size_t)wave * 2 + 0] = q0;
    q[(size_t)wave * 2 + 1] = q1;
  }
}

// ---------------- edge output ----------------
__global__ void k_edge(const int* __restrict__ src, const int* __restrict__ dst,
                       const float* __restrict__ p, const float* __restrict__ q,
                       const float* __restrict__ eb, float* __restrict__ eout, int E) {
  int e = blockIdx.x * blockDim.x + threadIdx.x;
  if (e < E) {
    int s = src[e], d = dst[e];
    float2 P = *reinterpret_cast<const float2*>(p + (size_t)s * 2);
    float2 Q = *reinterpret_cast<const float2*>(q + (size_t)d * 2);
    float2 o;
    o.x = P.x + Q.x + eb[0];
    o.y = P.y + Q.y + eb[1];
    *reinterpret_cast<float2*>(eout + (size_t)e * 2) = o;
  }
}

extern "C" void kernel_launch(void* const* d_in, const int* in_sizes, int n_in,
                              void* d_out, int out_size, void* d_ws, size_t ws_size,
                              hipStream_t stream) {
  const float* x   = (const float*)d_in[0];
  const int*   ei  = (const int*)d_in[1];
  const float* W1  = (const float*)d_in[2];
  const float* b1  = (const float*)d_in[3];
  const float* W2  = (const float*)d_in[4];
  const float* b2  = (const float*)d_in[5];
  const float* nW  = (const float*)d_in[6];
  const float* nb  = (const float*)d_in[7];
  const float* eW  = (const float*)d_in[8];
  const float* eb  = (const float*)d_in[9];

  const int N = in_sizes[0] / DIN;   // 50000
  const int E = in_sizes[1] / 2;     // 800000
  const int* src = ei;
  const int* dst = ei + E;

  float* ws   = (float*)d_ws;
  float* dinv = ws;                              // N
  float* p    = dinv + N;                        // 2N
  float* q    = p + 2 * (size_t)N;               // 2N
  _Float16* xh    = (_Float16*)(q + 2 * (size_t)N);  // 64N
  _Float16* aggxh = xh + (size_t)DIN * N;            // 64N
  _Float16* h     = aggxh + (size_t)DIN * N;         // 256N
  _Float16* xw2h  = h + (size_t)H1 * N;              // 128N
  _Float16* emb   = xw2h + (size_t)H2 * N;           // 128N
  _Float16* Wf1   = emb + (size_t)H2 * N;            // DIN*H1 = 16384
  _Float16* Wf2   = Wf1 + DIN * H1;                  // H1*H2 = 32768
  int* hist = (int*)(Wf2 + H1 * H2);                 // N (reused as cursor)
  int* offs = hist + N;                              // N+1
  int* bsum = offs + N + 1;                          // 64
  int* csr  = bsum + 64;                             // E

  float* node_out = (float*)d_out;                   // 2N
  float* edge_out = (float*)d_out + 2 * (size_t)N;   // 2E

  const int nb_blk = (N + 1023) / 1024;

  // ---- CSR build ----
  hipMemsetAsync(hist, 0, (size_t)N * sizeof(int), stream);
  k_hist<<<(E + 255) / 256, 256, 0, stream>>>(dst, hist, E);
  k_dinv<<<(N + 255) / 256, 256, 0, stream>>>(hist, dinv, N);
  k_scan1<<<nb_blk, 256, 0, stream>>>(hist, offs, bsum, N);
  k_scan2<<<1, 64, 0, stream>>>(bsum, offs, nb_blk, N, E);
  k_scan3<<<nb_blk, 256, 0, stream>>>(offs, bsum, N);
  hipMemsetAsync(hist, 0, (size_t)N * sizeof(int), stream);
  k_build<<<(E + 255) / 256, 256, 0, stream>>>(src, dst, offs, hist, csr, E);

  // ---- W fragment tables + x cast ----
  k_wfrag<DIN, H1><<<(DIN * H1 + 255) / 256, 256, 0, stream>>>(W1, Wf1);
  k_wfrag<H1, H2><<<(H1 * H2 + 255) / 256, 256, 0, stream>>>(W2, Wf2);
  k_cast<<<((N * DIN / 8) + 255) / 256, 256, 0, stream>>>(x, xh, N * DIN / 8);

  // ---- layer 1: aggregate-then-transform (DIN=64 < H1=256) ----
  k_gather<DIN, false><<<(N + 3) / 4, 256, 0, stream>>>(offs, csr, dinv, xh, nullptr, aggxh, N);
  k_mgemm<DIN, H1, true, true><<<(N + 127) / 128, 256, 0, stream>>>(aggxh, Wf1, b1, h, N);

  // ---- layer 2: transform-then-aggregate (H2=128 < H1=256) ----
  k_mgemm<H1, H2, false, false><<<(N + 127) / 128, 256, 0, stream>>>(h, Wf2, nullptr, xw2h, N);
  k_gather<H2, true><<<(N + 3) / 4, 256, 0, stream>>>(offs, csr, dinv, xw2h, b2, emb, N);

  // ---- heads + edge output ----
  k_heads<<<(N + 3) / 4, 256, 0, stream>>>(emb, nW, nb, eW, node_out, p, q, N);
  k_edge<<<(E + 255) / 256, 256, 0, stream>>>(src, dst, p, q, eb, edge_out, E);
}

// Round 6
// 219.443 us; speedup vs baseline: 16.2103x; 1.1843x over previous
//
#include <hip/hip_runtime.h>

static constexpr int DIN = 64;
static constexpr int H1  = 256;
static constexpr int H2  = 128;

using half8 = _Float16 __attribute__((ext_vector_type(8)));
using half4 = _Float16 __attribute__((ext_vector_type(4)));
using f32x4 = float __attribute__((ext_vector_type(4)));

// ---------------- zero int buffer ----------------
__global__ void k_zero(int* __restrict__ ptr, int n) {
  int i = blockIdx.x * blockDim.x + threadIdx.x;
  if (i < n) ptr[i] = 0;
}

// ---------------- degree histogram + per-edge rank ----------------
__global__ void k_hist(const int* __restrict__ dst, int* __restrict__ hist,
                       unsigned short* __restrict__ rank, int E) {
  int e = blockIdx.x * blockDim.x + threadIdx.x;
  if (e < E) {
    int old = atomicAdd(&hist[dst[e]], 1);
    rank[e] = (unsigned short)old;
  }
}

__global__ void k_dinv(const int* __restrict__ hist, float* __restrict__ dinv, int N) {
  int i = blockIdx.x * blockDim.x + threadIdx.x;
  if (i < N) dinv[i] = rsqrtf((float)hist[i] + 1.0f);   // +1 self-loop
}

// ---------------- hierarchical exclusive scan: hist[N] -> offs[N+1] ----------------
__global__ void k_scan1(const int* __restrict__ hist, int* __restrict__ offs,
                        int* __restrict__ bsum, int N) {
  __shared__ int ws[4];
  const int t = threadIdx.x;
  const int base = blockIdx.x * 1024 + t * 4;
  int4 v = make_int4(0, 0, 0, 0);
  if (base + 3 < N) v = *(const int4*)(hist + base);
  else {
    if (base + 0 < N) v.x = hist[base + 0];
    if (base + 1 < N) v.y = hist[base + 1];
    if (base + 2 < N) v.z = hist[base + 2];
    if (base + 3 < N) v.w = hist[base + 3];
  }
  int tsum = v.x + v.y + v.z + v.w;
  int lane = t & 63, wid = t >> 6;
  int incl = tsum;
#pragma unroll
  for (int off = 1; off < 64; off <<= 1) {
    int u = __shfl_up(incl, off);
    if (lane >= off) incl += u;
  }
  if (lane == 63) ws[wid] = incl;
  __syncthreads();
  int wbase = 0;
  for (int w = 0; w < wid; ++w) wbase += ws[w];
  int excl = wbase + incl - tsum;
  int4 o;
  o.x = excl;
  o.y = excl + v.x;
  o.z = excl + v.x + v.y;
  o.w = excl + v.x + v.y + v.z;
  if (base + 3 < N) *(int4*)(offs + base) = o;
  else {
    if (base + 0 < N) offs[base + 0] = o.x;
    if (base + 1 < N) offs[base + 1] = o.y;
    if (base + 2 < N) offs[base + 2] = o.z;
    if (base + 3 < N) offs[base + 3] = o.w;
  }
  if (t == 255) bsum[blockIdx.x] = wbase + incl;
}

__global__ void k_scan2(int* __restrict__ bsum, int* __restrict__ offs,
                        int nb, int N, int E) {
  int t = threadIdx.x;
  int v = (t < nb) ? bsum[t] : 0;
  int incl = v;
#pragma unroll
  for (int off = 1; off < 64; off <<= 1) {
    int u = __shfl_up(incl, off);
    if (t >= off) incl += u;
  }
  if (t < nb) bsum[t] = incl - v;
  if (t == 0) offs[N] = E;
}

__global__ void k_scan3(int* __restrict__ offs, const int* __restrict__ bsum, int N) {
  if (blockIdx.x == 0) return;
  int b = bsum[blockIdx.x];
  int base = blockIdx.x * 1024 + threadIdx.x * 4;
  if (base + 3 < N) {
    int4 v = *(int4*)(offs + base);
    v.x += b; v.y += b; v.z += b; v.w += b;
    *(int4*)(offs + base) = v;
  } else {
    for (int k = 0; k < 4; ++k) if (base + k < N) offs[base + k] += b;
  }
}

// ---------------- atomic-free CSR build (u16 payload) ----------------
__global__ void k_build(const int* __restrict__ src, const int* __restrict__ dst,
                        const unsigned short* __restrict__ rank,
                        const int* __restrict__ offs,
                        unsigned short* __restrict__ csr, int E) {
  int e = blockIdx.x * blockDim.x + threadIdx.x;
  if (e < E) {
    int d = dst[e];
    int pos = offs[d] + (int)rank[e];
    __builtin_nontemporal_store((unsigned short)src[e], &csr[pos]);
  }
}

// ---------------- cast fp32 -> fp16, vector 8 ----------------
__global__ void k_cast(const float* __restrict__ x, _Float16* __restrict__ xh, int nvec8) {
  int i = blockIdx.x * blockDim.x + threadIdx.x;
  if (i < nvec8) {
    const float4* x4 = (const float4*)x;
    float4 a = x4[i * 2 + 0];
    float4 b = x4[i * 2 + 1];
    half8 h;
    h[0] = (_Float16)a.x; h[1] = (_Float16)a.y; h[2] = (_Float16)a.z; h[3] = (_Float16)a.w;
    h[4] = (_Float16)b.x; h[5] = (_Float16)b.y; h[6] = (_Float16)b.z; h[7] = (_Float16)b.w;
    *(half8*)(xh + (size_t)i * 8) = h;
  }
}

// ---------------- W[K][NOUT] fp32 -> B-fragment-ordered fp16 table ----------------
template<int K, int NOUT>
__global__ void k_wfrag(const float* __restrict__ W, _Float16* __restrict__ Wf) {
  int i = blockIdx.x * blockDim.x + threadIdx.x;
  if (i >= K * NOUT) return;
  int j    = i & 7;
  int lane = (i >> 3) & 63;
  int rest = i >> 9;
  int t    = rest % (K / 32);
  int c    = rest / (K / 32);
  int k    = t * 32 + (lane >> 4) * 8 + j;
  int col  = c * 16 + (lane & 15);
  Wf[i] = (_Float16)W[k * NOUT + col];
}

// ---------------- fused head weights: Wz = W2 @ [nW | eWtop | eWbot], consts ----------------
__global__ void k_wz(const float* __restrict__ W2, const float* __restrict__ nW,
                     const float* __restrict__ nb, const float* __restrict__ eW,
                     const float* __restrict__ b2,
                     float* __restrict__ Wz, float* __restrict__ consts) {
  int k = threadIdx.x;  // 256 threads, 1 block
  float acc[6] = {0, 0, 0, 0, 0, 0};
  for (int m = 0; m < H2; ++m) {
    float w = W2[k * H2 + m];
    acc[0] = fmaf(w, nW[m * 2 + 0], acc[0]);
    acc[1] = fmaf(w, nW[m * 2 + 1], acc[1]);
    acc[2] = fmaf(w, eW[m * 2 + 0], acc[2]);
    acc[3] = fmaf(w, eW[m * 2 + 1], acc[3]);
    acc[4] = fmaf(w, eW[(H2 + m) * 2 + 0], acc[4]);
    acc[5] = fmaf(w, eW[(H2 + m) * 2 + 1], acc[5]);
  }
#pragma unroll
  for (int c = 0; c < 6; ++c) Wz[k * 8 + c] = acc[c];
  Wz[k * 8 + 6] = 0.0f; Wz[k * 8 + 7] = 0.0f;
  if (k == 0) {
    float c0 = nb[0], c1 = nb[1], c2 = 0, c3 = 0, c4 = 0, c5 = 0;
    for (int m = 0; m < H2; ++m) {
      float b = b2[m];
      c0 = fmaf(b, nW[m * 2 + 0], c0);
      c1 = fmaf(b, nW[m * 2 + 1], c1);
      c2 = fmaf(b, eW[m * 2 + 0], c2);
      c3 = fmaf(b, eW[m * 2 + 1], c3);
      c4 = fmaf(b, eW[(H2 + m) * 2 + 0], c4);
      c5 = fmaf(b, eW[(H2 + m) * 2 + 1], c5);
    }
    consts[0] = c0; consts[1] = c1; consts[2] = c2;
    consts[3] = c3; consts[4] = c4; consts[5] = c5;
    consts[6] = 0.0f; consts[7] = 0.0f;
  }
}

// ---------------- MFMA GEMM: C[M,NOUT] = A[M,K] @ W[K,NOUT], fused bias+relu ----------------
template<int K, int NOUT, bool BIAS, bool RELU>
__global__ __launch_bounds__(256) void
k_mgemm(const _Float16* __restrict__ A, const _Float16* __restrict__ Wf,
        const float* __restrict__ bias, _Float16* __restrict__ C, int M) {
  constexpr int NC = NOUT / 16;
  constexpr int NT = K / 32;
  const int wave = threadIdx.x >> 6;
  const int lane = threadIdx.x & 63;
  const int rowbase = blockIdx.x * 128 + wave * 32;
  if (rowbase >= M) return;
  const int r  = lane & 15;
  const int kb = lane >> 4;
  int row0 = rowbase + r;       if (row0 >= M) row0 = M - 1;
  int row1 = rowbase + 16 + r;  if (row1 >= M) row1 = M - 1;
  const _Float16* a0p = A + (size_t)row0 * K + kb * 8;
  const _Float16* a1p = A + (size_t)row1 * K + kb * 8;

  f32x4 acc[2][NC];
#pragma unroll
  for (int rb = 0; rb < 2; ++rb)
#pragma unroll
    for (int c = 0; c < NC; ++c) acc[rb][c] = (f32x4)0.0f;

#pragma unroll
  for (int t = 0; t < NT; ++t) {
    half8 a0 = *(const half8*)(a0p + t * 32);
    half8 a1 = *(const half8*)(a1p + t * 32);
#pragma unroll
    for (int c = 0; c < NC; ++c) {
      half8 bf = ((const half8*)Wf)[(size_t)(c * NT + t) * 64 + lane];
      acc[0][c] = __builtin_amdgcn_mfma_f32_16x16x32_f16(a0, bf, acc[0][c], 0, 0, 0);
      acc[1][c] = __builtin_amdgcn_mfma_f32_16x16x32_f16(a1, bf, acc[1][c], 0, 0, 0);
    }
  }

#pragma unroll
  for (int rb = 0; rb < 2; ++rb) {
    int growbase = rowbase + rb * 16 + kb * 4;
#pragma unroll
    for (int c = 0; c < NC; ++c) {
      int col = c * 16 + r;
      float bv = BIAS ? bias[col] : 0.0f;
#pragma unroll
      for (int j = 0; j < 4; ++j) {
        int grow = growbase + j;
        if (grow < M) {
          float v = acc[rb][c][j] + bv;
          if (RELU) v = fmaxf(v, 0.0f);
          C[(size_t)grow * NOUT + col] = (_Float16)v;
        }
      }
    }
  }
}

// ---------------- CSR gather (fp16 payload, fp32 accumulate) ----------------
template<int C, bool BIAS>
__global__ __launch_bounds__(256) void
k_gather(const int* __restrict__ offs, const unsigned short* __restrict__ csr,
         const float* __restrict__ dinv, const _Float16* __restrict__ xw,
         const float* __restrict__ bias, _Float16* __restrict__ out, int N) {
  constexpr int GSIZE = C / 8;
  constexpr int NE    = 64 / GSIZE;
  int wave = (int)((blockIdx.x * (size_t)blockDim.x + threadIdx.x) >> 6);
  int lane = threadIdx.x & 63;
  if (wave >= N) return;
  int group = lane / GSIZE;
  int sub   = lane % GSIZE;
  int ch0   = sub * 8;
  float dv = dinv[wave];
  int j0 = offs[wave], j1 = offs[wave + 1];

  float acc[8];
  if (group == 0) {
    half8 v = *(const half8*)(xw + (size_t)wave * C + ch0);
    float sc = dv * dv;
#pragma unroll
    for (int k = 0; k < 8; ++k) acc[k] = (float)v[k] * sc;
  } else {
#pragma unroll
    for (int k = 0; k < 8; ++k) acc[k] = 0.0f;
  }

  for (int base = j0; base < j1; base += 64) {
    int myj = base + lane;
    int s_l = 0; float dv_l = 0.0f;
    if (myj < j1) { s_l = (int)csr[myj]; dv_l = dinv[s_l]; }
    int cnt = min(64, j1 - base);
    for (int k = 0; k < cnt; k += NE) {
      int idx = k + group;
      int   s = __shfl(s_l, idx);
      float c = __shfl(dv_l, idx) * dv;
      half8 v = *(const half8*)(xw + (size_t)s * C + ch0);
#pragma unroll
      for (int k2 = 0; k2 < 8; ++k2) acc[k2] = fmaf((float)v[k2], c, acc[k2]);
    }
  }

#pragma unroll
  for (int off = GSIZE; off < 64; off <<= 1) {
#pragma unroll
    for (int k = 0; k < 8; ++k) acc[k] += __shfl_xor(acc[k], off);
  }

  if (group == 0) {
    half8 o;
#pragma unroll
    for (int k = 0; k < 8; ++k) {
      float v = acc[k] + (BIAS ? bias[ch0 + k] : 0.0f);
      o[k] = (_Float16)v;
    }
    *(half8*)(out + (size_t)wave * C + ch0) = o;
  }
}

// ---------------- z = h @ Wz  (one wave per node, 6 outputs padded to 8) ----------------
__global__ __launch_bounds__(256) void
k_z(const _Float16* __restrict__ h, const float* __restrict__ Wz,
    float* __restrict__ z, int N) {
  int wave = (int)((blockIdx.x * (size_t)blockDim.x + threadIdx.x) >> 6);
  int lane = threadIdx.x & 63;
  if (wave >= N) return;
  half4 hv = *(const half4*)(h + (size_t)wave * H1 + lane * 4);
  float zc[6] = {0, 0, 0, 0, 0, 0};
#pragma unroll
  for (int j = 0; j < 4; ++j) {
    float a = (float)hv[j];
    const float* wr = Wz + (lane * 4 + j) * 8;
#pragma unroll
    for (int c = 0; c < 6; ++c) zc[c] = fmaf(a, wr[c], zc[c]);
  }
#pragma unroll
  for (int off = 1; off < 64; off <<= 1) {
#pragma unroll
    for (int c = 0; c < 6; ++c) zc[c] += __shfl_xor(zc[c], off);
  }
  if (lane == 0) {
    float4 lo = make_float4(zc[0], zc[1], zc[2], zc[3]);
    float4 hi = make_float4(zc[4], zc[5], 0.0f, 0.0f);
    *(float4*)(z + (size_t)wave * 8)     = lo;
    *(float4*)(z + (size_t)wave * 8 + 4) = hi;
  }
}

// ---------------- aggregate z (C=8 fp32) -> node_out, p, q ----------------
__global__ __launch_bounds__(256) void
k_gatherz(const int* __restrict__ offs, const unsigned short* __restrict__ csr,
          const float* __restrict__ dinv, const float* __restrict__ z,
          const float* __restrict__ consts,
          float* __restrict__ node_out, float* __restrict__ p, float* __restrict__ q,
          int N) {
  int wave = (int)((blockIdx.x * (size_t)blockDim.x + threadIdx.x) >> 6);
  int lane = threadIdx.x & 63;
  if (wave >= N) return;
  int group = lane >> 1;     // 32 edge-groups
  int sub   = lane & 1;      // which float4 half of the row
  float dv = dinv[wave];
  int j0 = offs[wave], j1 = offs[wave + 1];

  float4 acc = make_float4(0.0f, 0.0f, 0.0f, 0.0f);
  if (group == 0) {
    float4 v = *(const float4*)(z + (size_t)wave * 8 + sub * 4);
    float sc = dv * dv;
    acc = make_float4(v.x * sc, v.y * sc, v.z * sc, v.w * sc);
  }

  for (int base = j0; base < j1; base += 64) {
    int myj = base + lane;
    int s_l = 0; float dv_l = 0.0f;
    if (myj < j1) { s_l = (int)csr[myj]; dv_l = dinv[s_l]; }
    int cnt = min(64, j1 - base);
    for (int k = 0; k < cnt; k += 32) {
      int idx = k + group;
      int   s = __shfl(s_l, idx);
      float c = __shfl(dv_l, idx) * dv;
      float4 v = *(const float4*)(z + (size_t)s * 8 + sub * 4);
      acc.x = fmaf(v.x, c, acc.x);
      acc.y = fmaf(v.y, c, acc.y);
      acc.z = fmaf(v.z, c, acc.z);
      acc.w = fmaf(v.w, c, acc.w);
    }
  }

#pragma unroll
  for (int off = 2; off < 64; off <<= 1) {
    acc.x += __shfl_xor(acc.x, off);
    acc.y += __shfl_xor(acc.y, off);
    acc.z += __shfl_xor(acc.z, off);
    acc.w += __shfl_xor(acc.w, off);
  }

  if (lane == 0) {            // channels 0..3: node_x(2), p(2)
    float2 no = make_float2(acc.x + consts[0], acc.y + consts[1]);
    float2 pp = make_float2(acc.z + consts[2], acc.w + consts[3]);
    *(float2*)(node_out + (size_t)wave * 2) = no;
    *(float2*)(p + (size_t)wave * 2) = pp;
  } else if (lane == 1) {     // channels 4..7: q(2)
    float2 qq = make_float2(acc.x + consts[4], acc.y + consts[5]);
    *(float2*)(q + (size_t)wave * 2) = qq;
  }
}

// ---------------- edge output ----------------
__global__ void k_edge(const int* __restrict__ src, const int* __restrict__ dst,
                       const float* __restrict__ p, const float* __restrict__ q,
                       const float* __restrict__ eb, float* __restrict__ eout, int E) {
  int e = blockIdx.x * blockDim.x + threadIdx.x;
  if (e < E) {
    int s = src[e], d = dst[e];
    float2 P = *reinterpret_cast<const float2*>(p + (size_t)s * 2);
    float2 Q = *reinterpret_cast<const float2*>(q + (size_t)d * 2);
    float2 o;
    o.x = P.x + Q.x + eb[0];
    o.y = P.y + Q.y + eb[1];
    *reinterpret_cast<float2*>(eout + (size_t)e * 2) = o;
  }
}

extern "C" void kernel_launch(void* const* d_in, const int* in_sizes, int n_in,
                              void* d_out, int out_size, void* d_ws, size_t ws_size,
                              hipStream_t stream) {
  const float* x   = (const float*)d_in[0];
  const int*   ei  = (const int*)d_in[1];
  const float* W1  = (const float*)d_in[2];
  const float* b1  = (const float*)d_in[3];
  const float* W2  = (const float*)d_in[4];
  const float* b2  = (const float*)d_in[5];
  const float* nW  = (const float*)d_in[6];
  const float* nb  = (const float*)d_in[7];
  const float* eW  = (const float*)d_in[8];
  const float* eb  = (const float*)d_in[9];

  const int N = in_sizes[0] / DIN;   // 50000
  const int E = in_sizes[1] / 2;     // 800000
  const int* src = ei;
  const int* dst = ei + E;

  // ---- workspace layout ----
  float* fws   = (float*)d_ws;
  float* dinv  = fws;                            // N
  float* p     = dinv + N;                       // 2N
  float* q     = p + 2 * (size_t)N;              // 2N
  float* z     = q + 2 * (size_t)N;              // 8N
  float* Wz    = z + 8 * (size_t)N;              // 2048
  float* consts = Wz + 2048;                     // 8
  _Float16* xh    = (_Float16*)(consts + 8);     // 64N
  _Float16* aggxh = xh + (size_t)DIN * N;        // 64N
  _Float16* h     = aggxh + (size_t)DIN * N;     // 256N
  _Float16* Wf1   = h + (size_t)H1 * N;          // DIN*H1 = 16384
  int* hist = (int*)(Wf1 + DIN * H1);            // N
  int* offs = hist + N;                          // N+1
  int* bsum = offs + N + 1;                      // 64 (pad to keep alignment)
  unsigned short* rank = (unsigned short*)(bsum + 64);   // E
  unsigned short* csr  = rank + E;                        // E

  float* node_out = (float*)d_out;                   // 2N
  float* edge_out = (float*)d_out + 2 * (size_t)N;   // 2E

  const int nb_blk = (N + 1023) / 1024;

  // ---- CSR build ----
  k_zero<<<(N + 255) / 256, 256, 0, stream>>>(hist, N);
  k_hist<<<(E + 255) / 256, 256, 0, stream>>>(dst, hist, rank, E);
  k_dinv<<<(N + 255) / 256, 256, 0, stream>>>(hist, dinv, N);
  k_scan1<<<nb_blk, 256, 0, stream>>>(hist, offs, bsum, N);
  k_scan2<<<1, 64, 0, stream>>>(bsum, offs, nb_blk, N, E);
  k_scan3<<<nb_blk, 256, 0, stream>>>(offs, bsum, N);
  k_build<<<(E + 255) / 256, 256, 0, stream>>>(src, dst, rank, offs, csr, E);

  // ---- weight prep + x cast ----
  k_wfrag<DIN, H1><<<(DIN * H1 + 255) / 256, 256, 0, stream>>>(W1, Wf1);
  k_wz<<<1, 256, 0, stream>>>(W2, nW, nb, eW, b2, Wz, consts);
  k_cast<<<((N * DIN / 8) + 255) / 256, 256, 0, stream>>>(x, xh, N * DIN / 8);

  // ---- layer 1: aggregate-then-transform ----
  k_gather<DIN, false><<<(N + 3) / 4, 256, 0, stream>>>(offs, csr, dinv, xh, nullptr, aggxh, N);
  k_mgemm<DIN, H1, true, true><<<(N + 127) / 128, 256, 0, stream>>>(aggxh, Wf1, b1, h, N);

  // ---- fused layer-2 + heads: z = h@Wz, aggregate 6-dim z ----
  k_z<<<(N + 3) / 4, 256, 0, stream>>>(h, Wz, z, N);
  k_gatherz<<<(N + 3) / 4, 256, 0, stream>>>(offs, csr, dinv, z, consts, node_out, p, q, N);

  // ---- edge output ----
  k_edge<<<(E + 255) / 256, 256, 0, stream>>>(src, dst, p, q, eb, edge_out, E);
}